// Round 7
// baseline (13941.338 us; speedup 1.0000x reference)
//
#include <hip/hip_runtime.h>

typedef unsigned short ushort_t;
typedef unsigned int uint_t;
typedef __attribute__((ext_vector_type(8))) short short8;   // 8 bf16
typedef __attribute__((ext_vector_type(4))) float f32x4;
typedef __attribute__((ext_vector_type(4))) float float4_t;

#define B_ 32
#define T_ 512
#define H_ 512
#define XT_ 16384   // bf16 elems per timestep slot: 8wg * 32b * 64ch (blocked)

// ---------- bf16 helpers ----------
__device__ __forceinline__ float bf2f(ushort_t u) {
  union { unsigned int i; float f; } v; v.i = ((unsigned int)u) << 16; return v.f;
}
__device__ __forceinline__ ushort_t f2bf(float f) {
  union { float fv; unsigned int i; } v; v.fv = f;
  unsigned int x = v.i;
  x += 0x7fffu + ((x >> 16) & 1u);   // RNE
  return (ushort_t)(x >> 16);
}

// fast gate activations
__device__ __forceinline__ float fsig(float a) {
  return __builtin_amdgcn_rcpf(1.f + __expf(-a));
}
__device__ __forceinline__ float ftanh(float a) {
  return 1.f - 2.f * __builtin_amdgcn_rcpf(1.f + __expf(2.f * a));
}

// ---------- IC-coherent (device-wide) accesses: sc0 sc1 ----------
__device__ __forceinline__ void cload16(short8& d, const ushort_t* p) {
  asm volatile("global_load_dwordx4 %0, %1, off sc0 sc1" : "=v"(d) : "v"(p) : "memory");
}
__device__ __forceinline__ void cstore4(uint_t v, ushort_t* p) {
  asm volatile("global_store_dword %1, %0, off sc0 sc1" :: "v"(v), "v"(p) : "memory");
}
__device__ __forceinline__ void cstore16(const short8& v, ushort_t* p) {
  asm volatile("global_store_dwordx4 %1, %0, off sc0 sc1" :: "v"(v), "v"(p) : "memory");
}
__device__ __forceinline__ void cstoreb(unsigned char* p) {
  asm volatile("global_store_byte %0, %1, off sc0 sc1" :: "v"(p), "v"(1) : "memory");
}
#define WAIT_VM0 asm volatile("s_waitcnt vmcnt(0)" ::: "memory")
__device__ __forceinline__ void vfence(short8& v) { asm volatile("" : "+v"(v)); }

// poll a row of byte-flags (n4 ints = n4*4 bytes), all must be 1
__device__ __forceinline__ void poll_bytes(const unsigned char* row, int n4) {
  const int lane = threadIdx.x & 63;
  const uint_t* r = (const uint_t*)row;
  for (;;) {
    uint_t a = (lane < n4)
             ? __hip_atomic_load(r + lane, __ATOMIC_RELAXED, __HIP_MEMORY_SCOPE_AGENT)
             : 0x01010101u;
    if (__all(a == 0x01010101u)) break;
    __builtin_amdgcn_s_sleep(1);
  }
  asm volatile("" ::: "memory");   // no hoisting data loads above the poll
}

// ---------- prep kernels ----------
__global__ void prep_w(const float* __restrict__ Wih, const float* __restrict__ Whh,
                       ushort_t* __restrict__ WihBf, ushort_t* __restrict__ WhhBf) {
  int i = blockIdx.x * 256 + threadIdx.x;
  WihBf[i] = f2bf(Wih[i]);
  WhhBf[i] = f2bf(Whh[i]);
}
// x [B][T][H] fp32 -> blocked [T][wg:8][b:32][ch:64] bf16
__global__ void prep_x(const float* __restrict__ x, ushort_t* __restrict__ xA) {
  int i = blockIdx.x * 256 + threadIdx.x;
  int ch = i & 63;
  int b  = (i >> 6) & 31;
  int wg = (i >> 11) & 7;
  int t  = i >> 14;
  xA[i] = f2bf(x[((size_t)b * T_ + t) * H_ + wg * 64 + ch]);
}

// ---------- one GRU layer stage: 8 WGs x 1024 threads (16 waves) -----------
// Waves 0-7: x-GEMM (ct=w>>1, bh=w&1). Waves 8-15: h-GEMM.
// ct==0 waves are LOADERS: fetch 16KB B-panel from IC once, share via LDS in
// MFMA-fragment order (conflict-free 1KB block ds writes/reads). Non-loader
// waves never touch the IC for B-panels -> 4x less IC read traffic, and only
// 4 waves/WG poll flags. Flags are per-wave BYTES (no post-store barrier).
__device__ void gru_stage(
    const ushort_t* __restrict__ xin, ushort_t* __restrict__ xout,
    const ushort_t* __restrict__ Wih, const ushort_t* __restrict__ Whh,
    const float* __restrict__ bih, const float* __restrict__ bhh,
    ushort_t* __restrict__ hbuf,             // [2][8][32][64] bf16
    unsigned char* __restrict__ selfFl,      // [T][128] bytes (wg*16+wave)
    const unsigned char* __restrict__ inFl,  // [T][inN4*4] bytes or null (L0)
    int inN4, int wg, char* lds)
{
  const int tid  = threadIdx.x;
  const int lane = tid & 63;
  const int wave = tid >> 6;
  const int isH  = wave >> 3;
  const int wl   = wave & 7;
  const int ct   = wl >> 1, bh = wl & 1;
  const bool loader = (ct == 0);
  const int m16  = lane & 15, quad = lane >> 4;
  const int jb   = wg * 64;

  // Weight A-fragments in registers: A[m=lane&15][k=quad*8+j], 16 ch per wave
  const ushort_t* Wsel = isH ? Whh : Wih;
  short8 afrag[3][16];
#pragma unroll
  for (int g = 0; g < 3; ++g) {
    const ushort_t* wp = Wsel + (size_t)(g * H_ + jb + ct * 16 + m16) * H_ + quad * 8;
#pragma unroll
    for (int kk = 0; kk < 16; ++kk)
      afrag[g][kk] = *(const short8*)(wp + kk * 32);
  }

  char* stage = lds + isH * 32768;          // 32KB x-stage, 32KB h-stage
  float* Gx = (float*)(lds + 65536);        // [192][33] fp32
  float* Gh = Gx + 192 * 33;
  float* Gmine = isH ? Gh : Gx;
  const int fragoff = (bh * 1024 + quad * 16 + m16) * 16;  // stage byte offset
  const int colbase = (bh * 16 + m16) * 64 + quad * 8;     // IC panel offset

  // gate mapping: b0 = tid>>5, channel pair c0,c1 = (tid&31)*2, +1
  const int b0 = tid >> 5;
  const int c0 = (tid & 31) * 2, c1 = c0 + 1;
  const float bxr0 = bih[0*H_ + jb + c0], bhr0 = bhh[0*H_ + jb + c0];
  const float bxz0 = bih[1*H_ + jb + c0], bhz0 = bhh[1*H_ + jb + c0];
  const float bxn0 = bih[2*H_ + jb + c0], bhn0 = bhh[2*H_ + jb + c0];
  const float bxr1 = bih[0*H_ + jb + c1], bhr1 = bhh[0*H_ + jb + c1];
  const float bxz1 = bih[1*H_ + jb + c1], bhz1 = bhh[1*H_ + jb + c1];
  const float bxn1 = bih[2*H_ + jb + c1], bhn1 = bhh[2*H_ + jb + c1];
  float hp0 = 0.f, hp1 = 0.f;

  for (int s = 0; s < T_; ++s) {
    f32x4 acc0 = {0.f, 0.f, 0.f, 0.f};
    f32x4 acc1 = acc0, acc2 = acc0;
    short8 bfr[16];
    const bool active = !isH || (s > 0);

    if (active && loader) {
      if (!isH) {
        const ushort_t* src = xin + (size_t)s * XT_ + colbase;
        if (inFl) {
          poll_bytes(inFl + (size_t)s * inN4 * 4, inN4);
#pragma unroll
          for (int kk = 0; kk < 16; ++kk)
            cload16(bfr[kk], src + (kk >> 1) * 2048 + (kk & 1) * 32);
          WAIT_VM0;
#pragma unroll
          for (int kk = 0; kk < 16; ++kk) vfence(bfr[kk]);
        } else {
          // L0: prior-dispatch input, plain cached loads
#pragma unroll
          for (int kk = 0; kk < 16; ++kk)
            bfr[kk] = *(const short8*)(src + (kk >> 1) * 2048 + (kk & 1) * 32);
        }
      } else {
        poll_bytes(selfFl + (size_t)(s - 1) * 128, 32);   // own-layer h flags
        const ushort_t* src = hbuf + (size_t)(s & 1) * XT_ + colbase;
#pragma unroll
        for (int kk = 0; kk < 16; ++kk)
          cload16(bfr[kk], src + (kk >> 1) * 2048 + (kk & 1) * 32);
        WAIT_VM0;
#pragma unroll
        for (int kk = 0; kk < 16; ++kk) vfence(bfr[kk]);
      }
      // share panel via LDS in fragment order (contiguous 1KB block writes)
#pragma unroll
      for (int kk = 0; kk < 16; ++kk)
        *(short8*)(stage + fragoff + kk * 1024) = bfr[kk];
    }
    __syncthreads();   // B1: stage ready; also fences gate-reads(s-1) vs G-writes(s)

    if (active) {
      if (loader) {
#pragma unroll
        for (int kk = 0; kk < 16; ++kk) {
          acc0 = __builtin_amdgcn_mfma_f32_16x16x32_bf16(afrag[0][kk], bfr[kk], acc0, 0, 0, 0);
          acc1 = __builtin_amdgcn_mfma_f32_16x16x32_bf16(afrag[1][kk], bfr[kk], acc1, 0, 0, 0);
          acc2 = __builtin_amdgcn_mfma_f32_16x16x32_bf16(afrag[2][kk], bfr[kk], acc2, 0, 0, 0);
        }
      } else {
#pragma unroll
        for (int kk = 0; kk < 16; ++kk) {
          short8 fr = *(const short8*)(stage + fragoff + kk * 1024);
          acc0 = __builtin_amdgcn_mfma_f32_16x16x32_bf16(afrag[0][kk], fr, acc0, 0, 0, 0);
          acc1 = __builtin_amdgcn_mfma_f32_16x16x32_bf16(afrag[1][kk], fr, acc1, 0, 0, 0);
          acc2 = __builtin_amdgcn_mfma_f32_16x16x32_bf16(afrag[2][kk], fr, acc2, 0, 0, 0);
        }
      }
    }

    // C/D: col = lane&15 (batch in bh-half), row = quad*4 + r (ch in ct-tile)
    {
      const int col = bh * 16 + m16;
#pragma unroll
      for (int r = 0; r < 4; ++r) {
        Gmine[(  0 + ct * 16 + quad * 4 + r) * 33 + col] = acc0[r];
        Gmine[( 64 + ct * 16 + quad * 4 + r) * 33 + col] = acc1[r];
        Gmine[(128 + ct * 16 + quad * 4 + r) * 33 + col] = acc2[r];
      }
    }
    __syncthreads();   // B2: G complete; also fences stage-reads(s) vs writes(s+1)

    // gate math (torch order r,z,n): n = tanh(xn + r*hn)
    {
      float rr = fsig(Gx[(  0 + c0) * 33 + b0] + bxr0 + Gh[(  0 + c0) * 33 + b0] + bhr0);
      float zz = fsig(Gx[( 64 + c0) * 33 + b0] + bxz0 + Gh[( 64 + c0) * 33 + b0] + bhz0);
      float nn = ftanh(Gx[(128 + c0) * 33 + b0] + bxn0 + rr * (Gh[(128 + c0) * 33 + b0] + bhn0));
      hp0 = (1.f - zz) * nn + zz * hp0;
    }
    {
      float rr = fsig(Gx[(  0 + c1) * 33 + b0] + bxr1 + Gh[(  0 + c1) * 33 + b0] + bhr1);
      float zz = fsig(Gx[( 64 + c1) * 33 + b0] + bxz1 + Gh[( 64 + c1) * 33 + b0] + bhz1);
      float nn = ftanh(Gx[(128 + c1) * 33 + b0] + bxn1 + rr * (Gh[(128 + c1) * 33 + b0] + bhn1));
      hp1 = (1.f - zz) * nn + zz * hp1;
    }
    uint_t pack = (uint_t)f2bf(hp0) | ((uint_t)f2bf(hp1) << 16);
    // coalesced IC stores: per wave 2 contiguous 128B rows for h and x
    cstore4(pack, hbuf + (size_t)((s + 1) & 1) * XT_ + wg * 2048 + b0 * 64 + c0);
    cstore4(pack, xout + (size_t)s * XT_ + wg * 2048 + b0 * 64 + c0);
    WAIT_VM0;                                   // this wave's stores acked in IC
    if (lane == 0)
      cstoreb(selfFl + (size_t)s * 128 + wg * 16 + wave);
  }
}

// ---------- LN stage: parity-split WGs (2 per LN), 16 waves = 32 rows -------
__device__ void ln_stage(
    const ushort_t* __restrict__ xin,
    ushort_t* __restrict__ xout_bf,       // mid-stack LN (blocked bf16 out)
    float* __restrict__ out_f32,          // final LN (fp32 d_out)
    const float* __restrict__ gamma, const float* __restrict__ beta,
    const int* __restrict__ seq,
    unsigned char* __restrict__ selfFl,   // [T][16] bytes or null
    const unsigned char* __restrict__ prodFl, int prodN4, int par)
{
  const int lane = threadIdx.x & 63;
  const int wv   = threadIdx.x >> 6;
  const int r0 = wv, r1 = wv + 16;
  const int len0 = seq[r0], len1 = seq[r1];
  const int off  = (lane >> 3) * 2048 + (lane & 7) * 8;   // blocked: h = lane*8

  float g[8], be[8];
#pragma unroll
  for (int j = 0; j < 8; ++j) { g[j] = gamma[lane * 8 + j]; be[j] = beta[lane * 8 + j]; }

  for (int s = par; s < T_; s += 2) {
    poll_bytes(prodFl + (size_t)s * prodN4 * 4, prodN4);
    short8 raw0, raw1;
    cload16(raw0, xin + (size_t)s * XT_ + off + r0 * 64);
    cload16(raw1, xin + (size_t)s * XT_ + off + r1 * 64);
    WAIT_VM0;
    vfence(raw0); vfence(raw1);

#pragma unroll
    for (int rr = 0; rr < 2; ++rr) {
      const short8& raw = rr ? raw1 : raw0;
      const int r = rr ? r1 : r0;
      const bool valid = s < (rr ? len1 : len0);
      float v[8];
#pragma unroll
      for (int j = 0; j < 8; ++j) v[j] = valid ? bf2f((ushort_t)raw[j]) : 0.f;
      float sum = 0.f, sq = 0.f;
#pragma unroll
      for (int j = 0; j < 8; ++j) { sum += v[j]; sq += v[j] * v[j]; }
#pragma unroll
      for (int o = 32; o > 0; o >>= 1) {
        sum += __shfl_xor(sum, o);
        sq  += __shfl_xor(sq, o);
      }
      float mu   = sum * (1.f / H_);
      float var  = sq * (1.f / H_) - mu * mu;
      float rstd = rsqrtf(var + 1e-5f);
      if (xout_bf) {
        short8 o8;
#pragma unroll
        for (int j = 0; j < 8; ++j)
          o8[j] = (short)f2bf((v[j] - mu) * rstd * g[j] + be[j]);
        cstore16(o8, xout_bf + (size_t)s * XT_ + off + r * 64);
      } else {
        float* dst = out_f32 + ((size_t)r * T_ + s) * H_ + lane * 8;
        float4_t o4a, o4b;
#pragma unroll
        for (int j = 0; j < 4; ++j) o4a[j] = (v[j] - mu) * rstd * g[j] + be[j];
#pragma unroll
        for (int j = 0; j < 4; ++j) o4b[j] = (v[4 + j] - mu) * rstd * g[4 + j] + be[4 + j];
        *(float4_t*)dst = o4a;
        *(float4_t*)(dst + 4) = o4b;
      }
    }
    if (selfFl) {
      WAIT_VM0;
      if (lane == 0) cstoreb(selfFl + (size_t)s * 16 + wv);
    }
  }
}

// ---------- fused pipelined kernel: 36 WGs x 1024 ---------------------------
// bids: [0,8) L0: xA->xB   [8,16) L1: xB->xC   [16,24) L2: xA->xC
//       [24,32) L3: xC->xB  32,33 LN0(par): xC->xA  34,35 LN1(par): xB->out
// Aliasing safe by flag causality (same acyclic chain as R4, verified).
__global__ __launch_bounds__(1024) void gru_mega(
    ushort_t* __restrict__ xA, ushort_t* __restrict__ xB, ushort_t* __restrict__ xC,
    const ushort_t* __restrict__ WihBf, const ushort_t* __restrict__ WhhBf,
    const float* __restrict__ bih, const float* __restrict__ bhh,
    const float* __restrict__ gamma, const float* __restrict__ beta,
    const int* __restrict__ seq,
    ushort_t* __restrict__ hbase, unsigned char* __restrict__ gfl,
    unsigned char* __restrict__ lnfl, float* __restrict__ out)
{
  extern __shared__ char lds[];
  const int bid = blockIdx.x;
  const int WM = 3 * H_ * H_;
  const int FL = T_ * 128;            // bytes per GRU layer flag array

  if (bid < 32) {
    const int layer = bid >> 3, wg = bid & 7;
    const ushort_t* xi; ushort_t* xo;
    const unsigned char* inFl; int inN4;
    if (layer == 0)      { xi = xA; xo = xB; inFl = nullptr;      inN4 = 0;  }
    else if (layer == 1) { xi = xB; xo = xC; inFl = gfl;          inN4 = 32; }
    else if (layer == 2) { xi = xA; xo = xC; inFl = lnfl;         inN4 = 4;  }
    else                 { xi = xC; xo = xB; inFl = gfl + 2 * FL; inN4 = 32; }
    gru_stage(xi, xo, WihBf + layer * WM, WhhBf + layer * WM,
              bih + layer * 1536, bhh + layer * 1536,
              hbase + layer * 2 * XT_, gfl + layer * FL, inFl, inN4, wg, lds);
  } else if (bid < 34) {
    ln_stage(xC, xA, nullptr, gamma, beta, seq, lnfl, gfl + 1 * FL, 32, bid - 32);
  } else {
    ln_stage(xB, nullptr, out, gamma + H_, beta + H_, seq,
             nullptr, gfl + 3 * FL, 32, bid - 34);
  }
}

// ---------- workspace layout (bytes) ----------
#define WIH_OFF 0u
#define WHH_OFF 6291456u
#define XA_OFF  12582912u
#define XB_OFF  29360128u
#define XC_OFF  46137344u
#define HB_OFF  62914560u             // 4 layers * 2*16384*2B = 262144
#define GFL_OFF 63176704u             // 4 * 512*128          = 262144
#define LNF_OFF 63438848u             // 512*16               = 8192
// memset: HB_OFF .. 63447040 (532480 B); ws total ~63.4 MB
#define LDS_BYTES 116224              // 2*32KB stage + 2*192*33*4 G

extern "C" void kernel_launch(void* const* d_in, const int* in_sizes, int n_in,
                              void* d_out, int out_size, void* d_ws, size_t ws_size,
                              hipStream_t stream) {
  (void)in_sizes; (void)n_in; (void)out_size; (void)ws_size;
  const float* x     = (const float*)d_in[0];
  const float* Wih   = (const float*)d_in[1];
  const float* Whh   = (const float*)d_in[2];
  const float* bih   = (const float*)d_in[3];
  const float* bhh   = (const float*)d_in[4];
  const float* gamma = (const float*)d_in[5];
  const float* beta  = (const float*)d_in[6];
  const int*   seq   = (const int*)d_in[7];

  char* ws = (char*)d_ws;
  ushort_t* WihBf = (ushort_t*)(ws + WIH_OFF);
  ushort_t* WhhBf = (ushort_t*)(ws + WHH_OFF);
  ushort_t* xA    = (ushort_t*)(ws + XA_OFF);
  ushort_t* xB    = (ushort_t*)(ws + XB_OFF);
  ushort_t* xC    = (ushort_t*)(ws + XC_OFF);
  ushort_t* hbase = (ushort_t*)(ws + HB_OFF);
  unsigned char* gfl  = (unsigned char*)(ws + GFL_OFF);
  unsigned char* lnf  = (unsigned char*)(ws + LNF_OFF);

  // zero h ping-pong + all flags (ws poisoned 0xAA before every timed call)
  hipMemsetAsync(ws + HB_OFF, 0, 532480u, stream);

  prep_w<<<12288, 256, 0, stream>>>(Wih, Whh, WihBf, WhhBf);
  prep_x<<<32768, 256, 0, stream>>>(x, xA);

  static int lds_set = 0;
  if (!lds_set) {
    hipFuncSetAttribute((const void*)gru_mega,
                        hipFuncAttributeMaxDynamicSharedMemorySize, LDS_BYTES);
    lds_set = 1;
  }
  gru_mega<<<36, 1024, LDS_BYTES, stream>>>(xA, xB, xC, WihBf, WhhBf,
                                            bih, bhh, gamma, beta, seq,
                                            hbase, gfl, lnf, (float*)d_out);
}